// Round 17
// baseline (933.407 us; speedup 1.0000x reference)
//
#include <hip/hip_runtime.h>
#include <hip/hip_bf16.h>

typedef __attribute__((ext_vector_type(4))) float f32x4;
typedef __attribute__((ext_vector_type(8))) short short8;
typedef __attribute__((ext_vector_type(8))) __bf16 bf16x8;
typedef __attribute__((ext_vector_type(8))) unsigned char u8x8;

union FragU { bf16x8 h; short8 s; };
union F8 { f32x4 v[2]; float f[8]; };

typedef const __attribute__((address_space(1))) void gvoid_t;
typedef __attribute__((address_space(3))) void lvoid_t;

static __device__ __forceinline__ void gload16(const void* g, void* l) {
  __builtin_amdgcn_global_load_lds((gvoid_t*)g, (lvoid_t*)l, 16, 0, 0);
}
// non-temporal variant: aux = CPol::NT (0x2) — read-once streams bypass L2 alloc
static __device__ __forceinline__ void gload16nt(const void* g, void* l) {
  __builtin_amdgcn_global_load_lds((gvoid_t*)g, (lvoid_t*)l, 16, 0, 2);
}

static __device__ __forceinline__ short8 cvt8(const f32x4 a0, const f32x4 a1) {
  bf16x8 hv;
  hv[0] = (__bf16)a0[0]; hv[1] = (__bf16)a0[1];
  hv[2] = (__bf16)a0[2]; hv[3] = (__bf16)a0[3];
  hv[4] = (__bf16)a1[0]; hv[5] = (__bf16)a1[1];
  hv[6] = (__bf16)a1[2]; hv[7] = (__bf16)a1[3];
  FragU u; u.h = hv; return u.s;
}

// pack 8 f32 in [0,1) -> u8 fixed-point (x*255, round-nearest)
static __device__ __forceinline__ unsigned long long pack8_u8(
    const f32x4 a0, const f32x4 a1) {
  F8 u; u.v[0] = a0; u.v[1] = a1;
  unsigned long long r = 0;
  #pragma unroll
  for (int j = 0; j < 8; ++j) {
    unsigned int q = (unsigned int)(u.f[j] * 255.f + 0.5f);
    r |= (unsigned long long)(q & 255u) << (8 * j);
  }
  return r;
}

// ---------------------------------------------------------------------------
// Layer-0 GEMM (bf16 MFMA) + u8 fixed-point fragment-cache production.
// r14 structure verbatim (BK=32, 2-buffer drain, 40 KB LDS -> 4 blocks/CU);
// NEW: A-staging loads are non-temporal (read-once, 1.6 GB stream) and the
// u8 cache stores are non-temporal (write-once, 445 MB stream) — keeps the
// reused B panels resident in L2.
// Cache tile: byte = kt*8192 + ks*4096 + (w*2+m)*512 + lane*8 + j.
// ---------------------------------------------------------------------------
__global__ __launch_bounds__(256) void gemm_l0(
    const float* __restrict__ Au, const __bf16* __restrict__ BTu,
    unsigned char* __restrict__ AcU, float* __restrict__ Pu,
    int Mu, int Ku, int KTu, int padKu,
    const float* __restrict__ Am, const __bf16* __restrict__ BTm,
    unsigned char* __restrict__ AcM, float* __restrict__ Pm,
    int Mm, int Km, int KTm, int padKm,
    int nbU, int rbU, int rbM)
{
  __shared__ float  sA[2][4096];   // 2 x 16 KB  [row(128)][granule(8)] gran-XOR-swz
  __shared__ __bf16 sB[2][2048];   // 2 x  4 KB  [row(64)][gran(4)x8] gran-XOR-swz

  const int t = threadIdx.x;
  const int w = t >> 6;
  const int lane = t & 63;
  const int r = lane & 15;
  const int g = lane >> 4;

  const float* A; const __bf16* BT; unsigned char* Ac; float* P;
  int M, K, KT, Kpad, rowBlk, split;
  {
    int bx = blockIdx.x;
    if (bx < nbU) {
      A = Au; BT = BTu; Ac = AcU; P = Pu; M = Mu; K = Ku; KT = KTu; Kpad = padKu;
      rowBlk = bx % rbU; split = bx / rbU;
    } else {
      int b2 = bx - nbU;
      A = Am; BT = BTm; Ac = AcM; P = Pm; M = Mm; K = Km; KT = KTm; Kpad = padKm;
      rowBlk = b2 % rbM; split = b2 / rbM;
    }
  }
  const int rowBase = rowBlk * 128;
  const int NS = Kpad >> 5;            // total 32-k steps
  const int s0 = split * 64;
  const int ns = min(64, NS - s0);     // >= 50 by config

  f32x4 acc[2][4];
  #pragma unroll
  for (int m = 0; m < 2; ++m)
    #pragma unroll
    for (int n = 0; n < 4; ++n)
      acc[m][n] = (f32x4){0.f, 0.f, 0.f, 0.f};

  const float* aRowP[4];
  int aOff[4];
  #pragma unroll
  for (int i = 0; i < 4; ++i) {
    int idx = i * 256 + t;
    int rr = idx >> 3;
    int p  = idx & 7;
    int rowg = rowBase + rr; if (rowg > M - 1) rowg = M - 1;
    aRowP[i] = A + (size_t)rowg * K;
    aOff[i] = (p ^ (rr & 7)) << 2;
  }
  const __bf16* bSrc = BT + (size_t)(w * 16 + (lane >> 2)) * Kpad
                     + (size_t)(((lane & 3) ^ ((lane >> 3) & 3)) * 8);

  auto stage = [&](int buf, int h) {
    const int kk = (s0 + h) * 32;
    #pragma unroll
    for (int i = 0; i < 4; ++i) {
      int ke = kk + aOff[i];
      if (ke > K - 4) ke = K - 4;
      gload16nt(aRowP[i] + ke, &sA[buf][i * 1024 + w * 256]);   // read-once: NT
    }
    gload16(bSrc + kk, &sB[buf][w * 512]);                      // reused: cached
  };

  auto cons = [&](int buf, int h) {
    const int k32 = s0 + h;
    const bool ok = (k32 * 32 + g * 8) < K;
    const short8 z8 = {0, 0, 0, 0, 0, 0, 0, 0};
    FragU aF[2], bF[4];
    unsigned long long a8[2];
    #pragma unroll
    for (int m = 0; m < 2; ++m) {
      const float* rowp = &sA[buf][(w * 32 + m * 16 + r) * 32];
      f32x4 a0 = *(const f32x4*)(rowp + (((2 * g)     ^ (r & 7)) << 2));
      f32x4 a1 = *(const f32x4*)(rowp + (((2 * g + 1) ^ (r & 7)) << 2));
      aF[m].s = ok ? cvt8(a0, a1) : z8;
      a8[m] = ok ? pack8_u8(a0, a1) : 0ull;
    }
    const int gb = g ^ ((r >> 1) & 3);
    #pragma unroll
    for (int n = 0; n < 4; ++n)
      bF[n].s = *(const short8*)&sB[buf][(n * 16 + r) * 32 + gb * 8];
    #pragma unroll
    for (int m = 0; m < 2; ++m)
      #pragma unroll
      for (int n = 0; n < 4; ++n)
        acc[m][n] = __builtin_amdgcn_mfma_f32_16x16x32_bf16(
            aF[m].s, bF[n].s, acc[m][n], 0, 0, 0);
    // u8 cache store: write-once stream -> non-temporal
    const int kt = k32 >> 1, ks = k32 & 1;
    unsigned char* cp = Ac + ((size_t)rowBlk * KT + kt) * 8192
                      + (size_t)ks * 4096 + (size_t)lane * 8;
    __builtin_nontemporal_store(a8[0],
        (unsigned long long*)(cp + (w * 2 + 0) * 512));
    __builtin_nontemporal_store(a8[1],
        (unsigned long long*)(cp + (w * 2 + 1) * 512));
  };

  stage(0, 0);

  for (int h = 0; h < ns; ++h) {
    asm volatile("s_waitcnt vmcnt(0)" ::: "memory");   // tile h landed
    __builtin_amdgcn_s_barrier();
    asm volatile("" ::: "memory");
    if (h + 1 < ns) stage((h + 1) & 1, h + 1);
    cons(h & 1, h);
  }

  // epilogue: C/D layout col = lane&15, row = (lane>>4)*4 + reg
  float* Pp = P + (size_t)split * M * 64;
  #pragma unroll
  for (int m = 0; m < 2; ++m) {
    #pragma unroll
    for (int j = 0; j < 4; ++j) {
      const int row = rowBase + w * 32 + m * 16 + g * 4 + j;
      if (row < M) {
        #pragma unroll
        for (int n = 0; n < 4; ++n)
          Pp[(size_t)row * 64 + n * 16 + r] = acc[m][n][j];
      }
    }
  }
}

// ---------------------------------------------------------------------------
// Layers 1-2 GEMM (r14 structure): u8 cache (A, unpacked to bf16, exact) x
// bf16 embeddings (B). BK=64, 2-buffer drain. NEW: A-cache staging loads are
// non-temporal (read-once 410 MB stream); B stays cached (reused).
// Epilogue scales acc by 1/255 (exact dequant).
// ---------------------------------------------------------------------------
__global__ __launch_bounds__(256) void gemm_l12(
    const unsigned char* __restrict__ AcU, const __bf16* __restrict__ BTu,
    float* __restrict__ Pu, int Mu, int KTu, int padKu,
    const unsigned char* __restrict__ AcM, const __bf16* __restrict__ BTm,
    float* __restrict__ Pm, int Mm, int KTm, int padKm,
    int nbU, int rbU, int rbM, int SPS)
{
  __shared__ unsigned char sA[2][8192];  // [ks(2)][slot(8)=w*2+m][lane(64)x8B]
  __shared__ __bf16 sB[2][4096];         // [half(2)][row(64)][gran(4)^swz][8]

  const int t = threadIdx.x;
  const int w = t >> 6;
  const int lane = t & 63;
  const int r = lane & 15;
  const int g = lane >> 4;

  const unsigned char* Ac; const __bf16* BT; float* P;
  int M, KT, Kpad, rowBlk, split;
  {
    int bx = blockIdx.x;
    if (bx < nbU) {
      Ac = AcU; BT = BTu; P = Pu; M = Mu; KT = KTu; Kpad = padKu;
      rowBlk = bx % rbU; split = bx / rbU;
    } else {
      int b2 = bx - nbU;
      Ac = AcM; BT = BTm; P = Pm; M = Mm; KT = KTm; Kpad = padKm;
      rowBlk = b2 % rbM; split = b2 / rbM;
    }
  }
  const int rowBase = rowBlk * 128;
  const int s0 = split * SPS;          // in 64-k tiles
  const int ns = min(SPS, KT - s0);

  f32x4 acc[2][4];
  #pragma unroll
  for (int m = 0; m < 2; ++m)
    #pragma unroll
    for (int n = 0; n < 4; ++n)
      acc[m][n] = (f32x4){0.f, 0.f, 0.f, 0.f};

  const unsigned char* aB = Ac + (size_t)rowBlk * KT * 8192
                          + (size_t)w * 1024 + (size_t)lane * 16;
  const int browl = w * 16 + (lane >> 2);
  const int bgr = (lane & 3) ^ ((browl >> 1) & 3);
  const __bf16* bB = BT + (size_t)browl * Kpad + (size_t)bgr * 8;

  auto stage = [&](int buf, int hh) {
    const size_t tb = (size_t)(s0 + hh) * 8192;
    gload16nt(aB + tb,        &sA[buf][w * 1024]);          // read-once: NT
    gload16nt(aB + tb + 4096, &sA[buf][4096 + w * 1024]);
    const int k0 = (s0 + hh) * 64;
    gload16(bB + k0,      &sB[buf][w * 512]);               // reused: cached
    gload16(bB + k0 + 32, &sB[buf][2048 + w * 512]);
  };

  auto cons = [&](int buf) {
    FragU aF[2][2], bF[2][4];
    #pragma unroll
    for (int ks = 0; ks < 2; ++ks) {
      #pragma unroll
      for (int m = 0; m < 2; ++m) {
        u8x8 by = *(const u8x8*)&sA[buf][ks * 4096 + (w * 2 + m) * 512 + lane * 8];
        bf16x8 hv;
        #pragma unroll
        for (int j = 0; j < 8; ++j) hv[j] = (__bf16)(float)by[j];  // exact
        aF[ks][m].h = hv;
      }
      #pragma unroll
      for (int n = 0; n < 4; ++n) {
        const int rowl = n * 16 + r;
        const int gg = g ^ ((rowl >> 1) & 3);
        bF[ks][n].s = *(const short8*)&sB[buf][ks * 2048 + rowl * 32 + gg * 8];
      }
    }
    #pragma unroll
    for (int ks = 0; ks < 2; ++ks)
      #pragma unroll
      for (int m = 0; m < 2; ++m)
        #pragma unroll
        for (int n = 0; n < 4; ++n)
          acc[m][n] = __builtin_amdgcn_mfma_f32_16x16x32_bf16(
              aF[ks][m].s, bF[ks][n].s, acc[m][n], 0, 0, 0);
  };

  stage(0, 0);

  for (int h = 0; h < ns; ++h) {
    asm volatile("s_waitcnt vmcnt(0)" ::: "memory");   // tile h landed
    __builtin_amdgcn_s_barrier();
    asm volatile("" ::: "memory");
    if (h + 1 < ns) stage((h + 1) & 1, h + 1);
    cons(h & 1);
  }

  const float inv = 1.f / 255.f;   // exact dequant of u8 fixed-point A
  float* Pp = P + (size_t)split * M * 64;
  #pragma unroll
  for (int m = 0; m < 2; ++m) {
    #pragma unroll
    for (int j = 0; j < 4; ++j) {
      const int row = rowBase + w * 32 + m * 16 + g * 4 + j;
      if (row < M) {
        #pragma unroll
        for (int n = 0; n < 4; ++n)
          Pp[(size_t)row * 64 + n * 16 + r] = acc[m][n][j] * inv;
      }
    }
  }
}

// ---------------------------------------------------------------------------
// Transpose + f32->bf16 convert with K padding:
//   in[K][64] f32 -> out[64][Kpad] bf16 (pad region zero-filled)
// ---------------------------------------------------------------------------
__global__ __launch_bounds__(256) void transpose_cvt(
    const float* __restrict__ in, __bf16* __restrict__ out, int K, int Kpad)
{
  __shared__ float tile[64][65];
  const int t = threadIdx.x;
  const int k0 = blockIdx.x * 64;
  #pragma unroll
  for (int i = 0; i < 4; ++i) {
    int f = t + i * 256;
    int k = f >> 4;
    int cc = (f & 15) << 2;
    if (k0 + k < K) {
      f32x4 v = *(const f32x4*)(in + (size_t)(k0 + k) * 64 + cc);
      tile[k][cc + 0] = v[0]; tile[k][cc + 1] = v[1];
      tile[k][cc + 2] = v[2]; tile[k][cc + 3] = v[3];
    }
  }
  __syncthreads();
  const int c = t >> 2;
  const int kc = (t & 3) << 4;
  #pragma unroll
  for (int h = 0; h < 2; ++h) {
    int kk = kc + h * 8;
    FragU p;
    if (k0 + kk < K) {
      #pragma unroll
      for (int j = 0; j < 8; ++j) p.h[j] = (__bf16)tile[kk + j][c];
    } else {
      p.s = (short8){0,0,0,0,0,0,0,0};
    }
    *(short8*)(out + (size_t)c * Kpad + k0 + kk) = p.s;
  }
}

// ---------------------------------------------------------------------------
// out[i][c] = LeakyReLU( (sum_s P[s][i][:] + self[i][:]) . W[c][:] + 2*b[c] )
// ---------------------------------------------------------------------------
__global__ __launch_bounds__(256) void layer_reduce(
    const float* __restrict__ P, int S,
    const float* __restrict__ self, const float* __restrict__ W,
    const float* __restrict__ b, float* __restrict__ out, int M)
{
  __shared__ float xs[4][64];
  const int t = threadIdx.x;
  const int c = t & 63;
  const int grp = t >> 6;
  const int row = blockIdx.x * 4 + grp;
  if (row < M) {
    float x = self[(size_t)row * 64 + c];
    for (int s = 0; s < S; ++s)
      x += P[(size_t)s * M * 64 + (size_t)row * 64 + c];
    xs[grp][c] = x;
  }
  __syncthreads();
  if (row >= M) return;
  float acc = 0.f;
  const f32x4* Wc = (const f32x4*)(W + c * 64);
  #pragma unroll
  for (int k4 = 0; k4 < 16; ++k4) {
    f32x4 wv = Wc[k4];
    acc += xs[grp][k4 * 4 + 0] * wv[0] + xs[grp][k4 * 4 + 1] * wv[1]
         + xs[grp][k4 * 4 + 2] * wv[2] + xs[grp][k4 * 4 + 3] * wv[3];
  }
  float v = acc + 2.0f * b[c];
  out[(size_t)row * 64 + c] = (v > 0.f) ? v : 0.01f * v;
}

// ---------------------------------------------------------------------------
__global__ __launch_bounds__(256) void gather_score(
    const int* __restrict__ uid, const int* __restrict__ mid,
    const float* __restrict__ u0, const float* __restrict__ u1,
    const float* __restrict__ u2, const float* __restrict__ u3,
    const float* __restrict__ m0, const float* __restrict__ m1,
    const float* __restrict__ m2, const float* __restrict__ m3,
    const float* __restrict__ oW, const float* __restrict__ ob,
    float* __restrict__ scores, int B)
{
  const int wave = threadIdx.x >> 6;
  const int lane = threadIdx.x & 63;
  const int b = blockIdx.x * 4 + wave;
  if (b >= B) return;
  const size_t ub = (size_t)uid[b] * 64 + lane;
  const size_t mb = (size_t)mid[b] * 64 + lane;
  float acc = u0[ub] * m0[mb] * oW[lane]
            + u1[ub] * m1[mb] * oW[64 + lane]
            + u2[ub] * m2[mb] * oW[128 + lane]
            + u3[ub] * m3[mb] * oW[192 + lane];
  #pragma unroll
  for (int off = 32; off > 0; off >>= 1)
    acc += __shfl_down(acc, off, 64);
  if (lane == 0) scores[b] = acc + ob[0];
}

// ---------------------------------------------------------------------------
extern "C" void kernel_launch(void* const* d_in, const int* in_sizes, int n_in,
                              void* d_out, int out_size, void* d_ws, size_t ws_size,
                              hipStream_t stream)
{
  const float* user_adj  = (const float*)d_in[0];
  const float* movie_adj = (const float*)d_in[1];
  const int*   user_id   = (const int*)d_in[2];
  const int*   movie_id  = (const int*)d_in[3];
  const float* user_emb  = (const float*)d_in[4];
  const float* movie_emb = (const float*)d_in[5];
  const float* user_Ws   = (const float*)d_in[6];
  const float* user_bs   = (const float*)d_in[7];
  const float* movie_Ws  = (const float*)d_in[8];
  const float* movie_bs  = (const float*)d_in[9];
  const float* out_W     = (const float*)d_in[10];
  const float* out_b     = (const float*)d_in[11];

  const int NU = 20000, NM = 10000, E = 64, B = 8192;
  const int rbU = 157, rbM = 79;          // ceil(M/128)
  const int KT_U = 157, KT_M = 313;       // ceil(K/64)
  const int NMpad = KT_U * 64;            // 10048
  const int NUpad = KT_M * 64;            // 20032
  const int SU = 5, SM = 10;              // k-splits
  const int SPS12 = 32;                   // 64-k tiles per split in l12

  char* ws = (char*)d_ws;
  size_t o = 0;
  unsigned char* Au8 = (unsigned char*)(ws + o); o += (size_t)rbU * KT_U * 8192;
  unsigned char* Am8 = (unsigned char*)(ws + o); o += (size_t)rbM * KT_M * 8192;
  float*  uP  = (float*)(ws + o);  o += (size_t)SU * NU * 64 * 4;
  float*  mP  = (float*)(ws + o);  o += (size_t)SM * NM * 64 * 4;
  float*  u1  = (float*)(ws + o);  o += (size_t)NU * 64 * 4;
  float*  u2  = (float*)(ws + o);  o += (size_t)NU * 64 * 4;
  float*  m1  = (float*)(ws + o);  o += (size_t)NM * 64 * 4;
  float*  m2  = (float*)(ws + o);  o += (size_t)NM * 64 * 4;
  __bf16* uT  = (__bf16*)(ws + o); o += (size_t)64 * NUpad * 2;
  __bf16* mT  = (__bf16*)(ws + o); o += (size_t)64 * NMpad * 2;

  float* scores = (float*)d_out;
  float* u3 = scores + B;
  float* m3 = u3 + (size_t)NU * E;

  const int nbU = rbU * SU;   // 785
  const int nbM = rbM * SM;   // 790

  const float* uCur = user_emb;
  const float* mCur = movie_emb;
  for (int l = 0; l < 3; ++l) {
    float* uNext = (l == 0) ? u1 : (l == 1) ? u2 : u3;
    float* mNext = (l == 0) ? m1 : (l == 1) ? m2 : m3;

    transpose_cvt<<<NMpad / 64, 256, 0, stream>>>(mCur, mT, NM, NMpad);
    transpose_cvt<<<NUpad / 64, 256, 0, stream>>>(uCur, uT, NU, NUpad);

    if (l == 0) {
      gemm_l0<<<nbU + nbM, 256, 0, stream>>>(
          user_adj, mT, Au8, uP, NU, NM, KT_U, NMpad,
          movie_adj, uT, Am8, mP, NM, NU, KT_M, NUpad,
          nbU, rbU, rbM);
    } else {
      gemm_l12<<<nbU + nbM, 256, 0, stream>>>(
          Au8, mT, uP, NU, KT_U, NMpad,
          Am8, uT, mP, NM, KT_M, NUpad,
          nbU, rbU, rbM, SPS12);
    }

    layer_reduce<<<(NU + 3) / 4, 256, 0, stream>>>(
        uP, SU, uCur, user_Ws + (size_t)l * E * E, user_bs + (size_t)l * E, uNext, NU);
    layer_reduce<<<(NM + 3) / 4, 256, 0, stream>>>(
        mP, SM, mCur, movie_Ws + (size_t)l * E * E, movie_bs + (size_t)l * E, mNext, NM);
    uCur = uNext; mCur = mNext;
  }
  gather_score<<<(B + 3) / 4, 256, 0, stream>>>(
      user_id, movie_id, user_emb, u1, u2, u3,
      movie_emb, m1, m2, m3, out_W, out_b, scores, B);
}

// Round 18
// 907.565 us; speedup vs baseline: 1.0285x; 1.0285x over previous
//
#include <hip/hip_runtime.h>
#include <hip/hip_bf16.h>

typedef __attribute__((ext_vector_type(4))) float f32x4;
typedef __attribute__((ext_vector_type(8))) short short8;
typedef __attribute__((ext_vector_type(8))) __bf16 bf16x8;
typedef __attribute__((ext_vector_type(8))) unsigned char u8x8;

union FragU { bf16x8 h; short8 s; };
union F8 { f32x4 v[2]; float f[8]; };

typedef const __attribute__((address_space(1))) void gvoid_t;
typedef __attribute__((address_space(3))) void lvoid_t;

static __device__ __forceinline__ void gload16(const void* g, void* l) {
  __builtin_amdgcn_global_load_lds((gvoid_t*)g, (lvoid_t*)l, 16, 0, 0);
}

static __device__ __forceinline__ short8 cvt8(const f32x4 a0, const f32x4 a1) {
  bf16x8 hv;
  hv[0] = (__bf16)a0[0]; hv[1] = (__bf16)a0[1];
  hv[2] = (__bf16)a0[2]; hv[3] = (__bf16)a0[3];
  hv[4] = (__bf16)a1[0]; hv[5] = (__bf16)a1[1];
  hv[6] = (__bf16)a1[2]; hv[7] = (__bf16)a1[3];
  FragU u; u.h = hv; return u.s;
}

// pack 8 f32 in [0,1) -> u8 fixed-point (x*255, round-nearest)
static __device__ __forceinline__ unsigned long long pack8_u8(
    const f32x4 a0, const f32x4 a1) {
  F8 u; u.v[0] = a0; u.v[1] = a1;
  unsigned long long r = 0;
  #pragma unroll
  for (int j = 0; j < 8; ++j) {
    unsigned int q = (unsigned int)(u.f[j] * 255.f + 0.5f);
    r |= (unsigned long long)(q & 255u) << (8 * j);
  }
  return r;
}

// ---------------------------------------------------------------------------
// Layer-0 GEMM (bf16 MFMA) + u8 fixed-point fragment-cache production.
// 2-buffer drain schedule (vmcnt(0) -> barrier -> stage(h+1) -> cons(h));
// LDS 40 KB -> 4 blocks/CU. [measured best: r14, 907.7 us total]
// Cache tile (128 rows x 64 k = 8192 B):
//   byte = kt*8192 + ks*4096 + (w*2+m)*512 + lane*8 + j.
// ---------------------------------------------------------------------------
__global__ __launch_bounds__(256) void gemm_l0(
    const float* __restrict__ Au, const __bf16* __restrict__ BTu,
    unsigned char* __restrict__ AcU, float* __restrict__ Pu,
    int Mu, int Ku, int KTu, int padKu,
    const float* __restrict__ Am, const __bf16* __restrict__ BTm,
    unsigned char* __restrict__ AcM, float* __restrict__ Pm,
    int Mm, int Km, int KTm, int padKm,
    int nbU, int rbU, int rbM)
{
  __shared__ float  sA[2][4096];   // 2 x 16 KB  [row(128)][granule(8)] gran-XOR-swz
  __shared__ __bf16 sB[2][2048];   // 2 x  4 KB  [row(64)][gran(4)x8] gran-XOR-swz

  const int t = threadIdx.x;
  const int w = t >> 6;
  const int lane = t & 63;
  const int r = lane & 15;
  const int g = lane >> 4;

  const float* A; const __bf16* BT; unsigned char* Ac; float* P;
  int M, K, KT, Kpad, rowBlk, split;
  {
    int bx = blockIdx.x;
    if (bx < nbU) {
      A = Au; BT = BTu; Ac = AcU; P = Pu; M = Mu; K = Ku; KT = KTu; Kpad = padKu;
      rowBlk = bx % rbU; split = bx / rbU;
    } else {
      int b2 = bx - nbU;
      A = Am; BT = BTm; Ac = AcM; P = Pm; M = Mm; K = Km; KT = KTm; Kpad = padKm;
      rowBlk = b2 % rbM; split = b2 / rbM;
    }
  }
  const int rowBase = rowBlk * 128;
  const int NS = Kpad >> 5;            // total 32-k steps
  const int s0 = split * 64;
  const int ns = min(64, NS - s0);     // >= 50 by config

  f32x4 acc[2][4];
  #pragma unroll
  for (int m = 0; m < 2; ++m)
    #pragma unroll
    for (int n = 0; n < 4; ++n)
      acc[m][n] = (f32x4){0.f, 0.f, 0.f, 0.f};

  const float* aRowP[4];
  int aOff[4];
  #pragma unroll
  for (int i = 0; i < 4; ++i) {
    int idx = i * 256 + t;
    int rr = idx >> 3;
    int p  = idx & 7;
    int rowg = rowBase + rr; if (rowg > M - 1) rowg = M - 1;
    aRowP[i] = A + (size_t)rowg * K;
    aOff[i] = (p ^ (rr & 7)) << 2;
  }
  const __bf16* bSrc = BT + (size_t)(w * 16 + (lane >> 2)) * Kpad
                     + (size_t)(((lane & 3) ^ ((lane >> 3) & 3)) * 8);

  auto stage = [&](int buf, int h) {
    const int kk = (s0 + h) * 32;
    #pragma unroll
    for (int i = 0; i < 4; ++i) {
      int ke = kk + aOff[i];
      if (ke > K - 4) ke = K - 4;
      gload16(aRowP[i] + ke, &sA[buf][i * 1024 + w * 256]);
    }
    gload16(bSrc + kk, &sB[buf][w * 512]);
  };

  auto cons = [&](int buf, int h) {
    const int k32 = s0 + h;
    const bool ok = (k32 * 32 + g * 8) < K;
    const short8 z8 = {0, 0, 0, 0, 0, 0, 0, 0};
    FragU aF[2], bF[4];
    unsigned long long a8[2];
    #pragma unroll
    for (int m = 0; m < 2; ++m) {
      const float* rowp = &sA[buf][(w * 32 + m * 16 + r) * 32];
      f32x4 a0 = *(const f32x4*)(rowp + (((2 * g)     ^ (r & 7)) << 2));
      f32x4 a1 = *(const f32x4*)(rowp + (((2 * g + 1) ^ (r & 7)) << 2));
      aF[m].s = ok ? cvt8(a0, a1) : z8;
      a8[m] = ok ? pack8_u8(a0, a1) : 0ull;
    }
    const int gb = g ^ ((r >> 1) & 3);
    #pragma unroll
    for (int n = 0; n < 4; ++n)
      bF[n].s = *(const short8*)&sB[buf][(n * 16 + r) * 32 + gb * 8];
    #pragma unroll
    for (int m = 0; m < 2; ++m)
      #pragma unroll
      for (int n = 0; n < 4; ++n)
        acc[m][n] = __builtin_amdgcn_mfma_f32_16x16x32_bf16(
            aF[m].s, bF[n].s, acc[m][n], 0, 0, 0);
    // u8 cache store: 64 lanes x 8 B contiguous (512 B) per slot
    const int kt = k32 >> 1, ks = k32 & 1;
    unsigned char* cp = Ac + ((size_t)rowBlk * KT + kt) * 8192
                      + (size_t)ks * 4096 + (size_t)lane * 8;
    *(unsigned long long*)(cp + (w * 2 + 0) * 512) = a8[0];
    *(unsigned long long*)(cp + (w * 2 + 1) * 512) = a8[1];
  };

  stage(0, 0);

  for (int h = 0; h < ns; ++h) {
    asm volatile("s_waitcnt vmcnt(0)" ::: "memory");   // tile h landed
    __builtin_amdgcn_s_barrier();
    asm volatile("" ::: "memory");
    if (h + 1 < ns) stage((h + 1) & 1, h + 1);
    cons(h & 1, h);
  }

  // epilogue: C/D layout col = lane&15, row = (lane>>4)*4 + reg
  float* Pp = P + (size_t)split * M * 64;
  #pragma unroll
  for (int m = 0; m < 2; ++m) {
    #pragma unroll
    for (int j = 0; j < 4; ++j) {
      const int row = rowBase + w * 32 + m * 16 + g * 4 + j;
      if (row < M) {
        #pragma unroll
        for (int n = 0; n < 4; ++n)
          Pp[(size_t)row * 64 + n * 16 + r] = acc[m][n][j];
      }
    }
  }
}

// ---------------------------------------------------------------------------
// Layers 1-2 GEMM: u8 cache (A, unpacked to bf16 in-register, exact) x bf16
// embeddings (B). BK = 64. 2-buffer drain schedule; LDS 24 KB -> 6 blocks/CU.
// Epilogue scales acc by 1/255 (exact dequant).
// ---------------------------------------------------------------------------
__global__ __launch_bounds__(256) void gemm_l12(
    const unsigned char* __restrict__ AcU, const __bf16* __restrict__ BTu,
    float* __restrict__ Pu, int Mu, int KTu, int padKu,
    const unsigned char* __restrict__ AcM, const __bf16* __restrict__ BTm,
    float* __restrict__ Pm, int Mm, int KTm, int padKm,
    int nbU, int rbU, int rbM, int SPS)
{
  __shared__ unsigned char sA[2][8192];  // [ks(2)][slot(8)=w*2+m][lane(64)x8B]
  __shared__ __bf16 sB[2][4096];         // [half(2)][row(64)][gran(4)^swz][8]

  const int t = threadIdx.x;
  const int w = t >> 6;
  const int lane = t & 63;
  const int r = lane & 15;
  const int g = lane >> 4;

  const unsigned char* Ac; const __bf16* BT; float* P;
  int M, KT, Kpad, rowBlk, split;
  {
    int bx = blockIdx.x;
    if (bx < nbU) {
      Ac = AcU; BT = BTu; P = Pu; M = Mu; KT = KTu; Kpad = padKu;
      rowBlk = bx % rbU; split = bx / rbU;
    } else {
      int b2 = bx - nbU;
      Ac = AcM; BT = BTm; P = Pm; M = Mm; KT = KTm; Kpad = padKm;
      rowBlk = b2 % rbM; split = b2 / rbM;
    }
  }
  const int rowBase = rowBlk * 128;
  const int s0 = split * SPS;          // in 64-k tiles
  const int ns = min(SPS, KT - s0);    // >= 25 by config

  f32x4 acc[2][4];
  #pragma unroll
  for (int m = 0; m < 2; ++m)
    #pragma unroll
    for (int n = 0; n < 4; ++n)
      acc[m][n] = (f32x4){0.f, 0.f, 0.f, 0.f};

  // A: wave w stages its 2 slots for both ks: 1024 B per gload
  const unsigned char* aB = Ac + (size_t)rowBlk * KT * 8192
                          + (size_t)w * 1024 + (size_t)lane * 16;
  // B: wave w stages rows [16w,16w+16): lane -> row = 16w+(lane>>2), gran=lane&3
  const int browl = w * 16 + (lane >> 2);
  const int bgr = (lane & 3) ^ ((browl >> 1) & 3);   // src-side swizzle
  const __bf16* bB = BT + (size_t)browl * Kpad + (size_t)bgr * 8;

  auto stage = [&](int buf, int hh) {
    const size_t tb = (size_t)(s0 + hh) * 8192;
    gload16(aB + tb,        &sA[buf][w * 1024]);          // ks = 0 slots
    gload16(aB + tb + 4096, &sA[buf][4096 + w * 1024]);   // ks = 1 slots
    const int k0 = (s0 + hh) * 64;
    gload16(bB + k0,      &sB[buf][w * 512]);             // half 0 (k 0..31)
    gload16(bB + k0 + 32, &sB[buf][2048 + w * 512]);      // half 1 (k 32..63)
  };

  auto cons = [&](int buf) {
    FragU aF[2][2], bF[2][4];
    #pragma unroll
    for (int ks = 0; ks < 2; ++ks) {
      #pragma unroll
      for (int m = 0; m < 2; ++m) {
        u8x8 by = *(const u8x8*)&sA[buf][ks * 4096 + (w * 2 + m) * 512 + lane * 8];
        bf16x8 hv;
        #pragma unroll
        for (int j = 0; j < 8; ++j) hv[j] = (__bf16)(float)by[j];  // exact
        aF[ks][m].h = hv;
      }
      #pragma unroll
      for (int n = 0; n < 4; ++n) {
        const int rowl = n * 16 + r;
        const int gg = g ^ ((rowl >> 1) & 3);   // read-side swizzle
        bF[ks][n].s = *(const short8*)&sB[buf][ks * 2048 + rowl * 32 + gg * 8];
      }
    }
    #pragma unroll
    for (int ks = 0; ks < 2; ++ks)
      #pragma unroll
      for (int m = 0; m < 2; ++m)
        #pragma unroll
        for (int n = 0; n < 4; ++n)
          acc[m][n] = __builtin_amdgcn_mfma_f32_16x16x32_bf16(
              aF[ks][m].s, bF[ks][n].s, acc[m][n], 0, 0, 0);
  };

  stage(0, 0);

  for (int h = 0; h < ns; ++h) {
    asm volatile("s_waitcnt vmcnt(0)" ::: "memory");   // tile h landed
    __builtin_amdgcn_s_barrier();
    asm volatile("" ::: "memory");
    if (h + 1 < ns) stage((h + 1) & 1, h + 1);
    cons(h & 1);
  }

  const float inv = 1.f / 255.f;   // exact dequant of u8 fixed-point A
  float* Pp = P + (size_t)split * M * 64;
  #pragma unroll
  for (int m = 0; m < 2; ++m) {
    #pragma unroll
    for (int j = 0; j < 4; ++j) {
      const int row = rowBase + w * 32 + m * 16 + g * 4 + j;
      if (row < M) {
        #pragma unroll
        for (int n = 0; n < 4; ++n)
          Pp[(size_t)row * 64 + n * 16 + r] = acc[m][n][j] * inv;
      }
    }
  }
}

// ---------------------------------------------------------------------------
// Transpose + f32->bf16 convert with K padding:
//   in[K][64] f32 -> out[64][Kpad] bf16 (pad region zero-filled)
// ---------------------------------------------------------------------------
__global__ __launch_bounds__(256) void transpose_cvt(
    const float* __restrict__ in, __bf16* __restrict__ out, int K, int Kpad)
{
  __shared__ float tile[64][65];
  const int t = threadIdx.x;
  const int k0 = blockIdx.x * 64;
  #pragma unroll
  for (int i = 0; i < 4; ++i) {
    int f = t + i * 256;
    int k = f >> 4;
    int cc = (f & 15) << 2;
    if (k0 + k < K) {
      f32x4 v = *(const f32x4*)(in + (size_t)(k0 + k) * 64 + cc);
      tile[k][cc + 0] = v[0]; tile[k][cc + 1] = v[1];
      tile[k][cc + 2] = v[2]; tile[k][cc + 3] = v[3];
    }
  }
  __syncthreads();
  const int c = t >> 2;
  const int kc = (t & 3) << 4;
  #pragma unroll
  for (int h = 0; h < 2; ++h) {
    int kk = kc + h * 8;
    FragU p;
    if (k0 + kk < K) {
      #pragma unroll
      for (int j = 0; j < 8; ++j) p.h[j] = (__bf16)tile[kk + j][c];
    } else {
      p.s = (short8){0,0,0,0,0,0,0,0};
    }
    *(short8*)(out + (size_t)c * Kpad + k0 + kk) = p.s;
  }
}

// ---------------------------------------------------------------------------
// out[i][c] = LeakyReLU( (sum_s P[s][i][:] + self[i][:]) . W[c][:] + 2*b[c] )
// ---------------------------------------------------------------------------
__global__ __launch_bounds__(256) void layer_reduce(
    const float* __restrict__ P, int S,
    const float* __restrict__ self, const float* __restrict__ W,
    const float* __restrict__ b, float* __restrict__ out, int M)
{
  __shared__ float xs[4][64];
  const int t = threadIdx.x;
  const int c = t & 63;
  const int grp = t >> 6;
  const int row = blockIdx.x * 4 + grp;
  if (row < M) {
    float x = self[(size_t)row * 64 + c];
    for (int s = 0; s < S; ++s)
      x += P[(size_t)s * M * 64 + (size_t)row * 64 + c];
    xs[grp][c] = x;
  }
  __syncthreads();
  if (row >= M) return;
  float acc = 0.f;
  const f32x4* Wc = (const f32x4*)(W + c * 64);
  #pragma unroll
  for (int k4 = 0; k4 < 16; ++k4) {
    f32x4 wv = Wc[k4];
    acc += xs[grp][k4 * 4 + 0] * wv[0] + xs[grp][k4 * 4 + 1] * wv[1]
         + xs[grp][k4 * 4 + 2] * wv[2] + xs[grp][k4 * 4 + 3] * wv[3];
  }
  float v = acc + 2.0f * b[c];
  out[(size_t)row * 64 + c] = (v > 0.f) ? v : 0.01f * v;
}

// ---------------------------------------------------------------------------
__global__ __launch_bounds__(256) void gather_score(
    const int* __restrict__ uid, const int* __restrict__ mid,
    const float* __restrict__ u0, const float* __restrict__ u1,
    const float* __restrict__ u2, const float* __restrict__ u3,
    const float* __restrict__ m0, const float* __restrict__ m1,
    const float* __restrict__ m2, const float* __restrict__ m3,
    const float* __restrict__ oW, const float* __restrict__ ob,
    float* __restrict__ scores, int B)
{
  const int wave = threadIdx.x >> 6;
  const int lane = threadIdx.x & 63;
  const int b = blockIdx.x * 4 + wave;
  if (b >= B) return;
  const size_t ub = (size_t)uid[b] * 64 + lane;
  const size_t mb = (size_t)mid[b] * 64 + lane;
  float acc = u0[ub] * m0[mb] * oW[lane]
            + u1[ub] * m1[mb] * oW[64 + lane]
            + u2[ub] * m2[mb] * oW[128 + lane]
            + u3[ub] * m3[mb] * oW[192 + lane];
  #pragma unroll
  for (int off = 32; off > 0; off >>= 1)
    acc += __shfl_down(acc, off, 64);
  if (lane == 0) scores[b] = acc + ob[0];
}

// ---------------------------------------------------------------------------
extern "C" void kernel_launch(void* const* d_in, const int* in_sizes, int n_in,
                              void* d_out, int out_size, void* d_ws, size_t ws_size,
                              hipStream_t stream)
{
  const float* user_adj  = (const float*)d_in[0];
  const float* movie_adj = (const float*)d_in[1];
  const int*   user_id   = (const int*)d_in[2];
  const int*   movie_id  = (const int*)d_in[3];
  const float* user_emb  = (const float*)d_in[4];
  const float* movie_emb = (const float*)d_in[5];
  const float* user_Ws   = (const float*)d_in[6];
  const float* user_bs   = (const float*)d_in[7];
  const float* movie_Ws  = (const float*)d_in[8];
  const float* movie_bs  = (const float*)d_in[9];
  const float* out_W     = (const float*)d_in[10];
  const float* out_b     = (const float*)d_in[11];

  const int NU = 20000, NM = 10000, E = 64, B = 8192;
  const int rbU = 157, rbM = 79;          // ceil(M/128)
  const int KT_U = 157, KT_M = 313;       // ceil(K/64)
  const int NMpad = KT_U * 64;            // 10048
  const int NUpad = KT_M * 64;            // 20032
  const int SU = 5, SM = 10;              // k-splits
  const int SPS12 = 32;                   // 64-k tiles per split in l12

  char* ws = (char*)d_ws;
  size_t o = 0;
  unsigned char* Au8 = (unsigned char*)(ws + o); o += (size_t)rbU * KT_U * 8192;
  unsigned char* Am8 = (unsigned char*)(ws + o); o += (size_t)rbM * KT_M * 8192;
  float*  uP  = (float*)(ws + o);  o += (size_t)SU * NU * 64 * 4;
  float*  mP  = (float*)(ws + o);  o += (size_t)SM * NM * 64 * 4;
  float*  u1  = (float*)(ws + o);  o += (size_t)NU * 64 * 4;
  float*  u2  = (float*)(ws + o);  o += (size_t)NU * 64 * 4;
  float*  m1  = (float*)(ws + o);  o += (size_t)NM * 64 * 4;
  float*  m2  = (float*)(ws + o);  o += (size_t)NM * 64 * 4;
  __bf16* uT  = (__bf16*)(ws + o); o += (size_t)64 * NUpad * 2;
  __bf16* mT  = (__bf16*)(ws + o); o += (size_t)64 * NMpad * 2;

  float* scores = (float*)d_out;
  float* u3 = scores + B;
  float* m3 = u3 + (size_t)NU * E;

  const int nbU = rbU * SU;   // 785
  const int nbM = rbM * SM;   // 790

  const float* uCur = user_emb;
  const float* mCur = movie_emb;
  for (int l = 0; l < 3; ++l) {
    float* uNext = (l == 0) ? u1 : (l == 1) ? u2 : u3;
    float* mNext = (l == 0) ? m1 : (l == 1) ? m2 : m3;

    transpose_cvt<<<NMpad / 64, 256, 0, stream>>>(mCur, mT, NM, NMpad);
    transpose_cvt<<<NUpad / 64, 256, 0, stream>>>(uCur, uT, NU, NUpad);

    if (l == 0) {
      gemm_l0<<<nbU + nbM, 256, 0, stream>>>(
          user_adj, mT, Au8, uP, NU, NM, KT_U, NMpad,
          movie_adj, uT, Am8, mP, NM, NU, KT_M, NUpad,
          nbU, rbU, rbM);
    } else {
      gemm_l12<<<nbU + nbM, 256, 0, stream>>>(
          Au8, mT, uP, NU, KT_U, NMpad,
          Am8, uT, mP, NM, KT_M, NUpad,
          nbU, rbU, rbM, SPS12);
    }

    layer_reduce<<<(NU + 3) / 4, 256, 0, stream>>>(
        uP, SU, uCur, user_Ws + (size_t)l * E * E, user_bs + (size_t)l * E, uNext, NU);
    layer_reduce<<<(NM + 3) / 4, 256, 0, stream>>>(
        mP, SM, mCur, movie_Ws + (size_t)l * E * E, movie_bs + (size_t)l * E, mNext, NM);
    uCur = uNext; mCur = mNext;
  }
  gather_score<<<(B + 3) / 4, 256, 0, stream>>>(
      user_id, movie_id, user_emb, u1, u2, u3,
      movie_emb, m1, m2, m3, out_W, out_b, scores, B);
}